// Round 1
// baseline (1661.402 us; speedup 1.0000x reference)
//
#include <hip/hip_runtime.h>
#include <climits>

#define NB 2
#define NPTS_ 16384
#define IMH 200
#define IMW 176
#define IMC 256
#define KTOT_ 2048
#define ROWS_ 4096
#define CIN_ 288
#define COUT_ 128

typedef unsigned long long u64;
typedef unsigned int u32;

// u64-key (dist_bits<<32 | ~compacted_idx) wave-max via DPP, result in lane 63.
// Both halves shifted with identical ctrl + bound_ctrl=false (keep own) -> pair stays consistent.
#define DPP_MAXK(lo, hi, ctrl)                                                                \
  do {                                                                                        \
    u32 _slo = (u32)__builtin_amdgcn_update_dpp((int)(lo), (int)(lo), (ctrl), 0xF, 0xF, false); \
    u32 _shi = (u32)__builtin_amdgcn_update_dpp((int)(hi), (int)(hi), (ctrl), 0xF, 0xF, false); \
    bool _g = (_shi > (hi)) || ((_shi == (hi)) && (_slo > (lo)));                             \
    (hi) = _g ? _shi : (hi);                                                                  \
    (lo) = _g ? _slo : (lo);                                                                  \
  } while (0)

// 16x16 grid cell for spatial ordering only (correctness does not depend on it).
__device__ __forceinline__ int cellof(int band, float x, float y) {
  float x0, xs, y0, ys;
  if (band == 0)      { x0 = 0.f; xs = 16.f / 25.f;  y0 = -25.f; ys = 16.f / 50.f; }
  else if (band == 1) { x0 = 0.f; xs = 16.f / 45.f;  y0 = -45.f; ys = 16.f / 90.f; }
  else                { x0 = 0.f; xs = 16.f / 70.4f; y0 = -40.f; ys = 16.f / 80.f; }
  int cx = (int)((x - x0) * xs); cx = min(max(cx, 0), 15);
  int cy = (int)((y - y0) * ys); cy = min(max(cy, 0), 15);
  return cy * 16 + cx;
}

// ---------------------------------------------------------------- FPS core (bbox-pruned, exact)
// Thread t owns blocked sorted slots [t*NL, t*NL+NL) (spatially contiguous after cell sort).
// Per step: if lb2(last, chunk bbox) >= chunkmax -> EXACT skip (every member's
// d(i,last) >= lb2 >= chunkmax >= dist[i], so min() is a no-op; 1e-4 margin covers fp rounding
// of the bound). Else full chunk update with the reference's exact fp32 sequence.
// Selection key = (dist_bits<<32)|~c  (c = compacted idx): u64 max == (max dist, tie -> min c)
// == jnp.argmax first-index tie-break. Pads: dist=0, c=0xFFFF -> lose to any real point.
template <int NW, int NL>
__device__ void fps_core(int tid, int wv, int M, int K, int base,
                         const float* __restrict__ pts,
                         const u32* __restrict__ s_ps,
                         float4* __restrict__ s_k,
                         u64 (* __restrict__ s_key)[16],
                         float4 (* __restrict__ s_cxyz)[16],
                         float4* __restrict__ s_first) {
#pragma clang fp contract(off)
  float lx[NL], ly[NL], lz[NL], ld[NL];
  int lc[NL];
  const int p0 = tid * NL;
  float bxmin = 1e30f, bxmax = -1e30f, bymin = 1e30f, bymax = -1e30f,
        bzmin = 1e30f, bzmax = -1e30f;
#pragma unroll
  for (int j = 0; j < NL; ++j) {
    int p = p0 + j;
    bool v = p < M;
    u32 pk = s_ps[v ? p : 0];
    int orig = (int)(pk & 0xFFFFu);
    int gi = (base + orig) * 5;
    float x = pts[gi + 1], y = pts[gi + 2], z = pts[gi + 3];
    lx[j] = x; ly[j] = y; lz[j] = z;
    ld[j] = v ? 1e10f : 0.0f;
    lc[j] = v ? (int)(pk >> 16) : 0xFFFF;
    if (v) {
      bxmin = fminf(bxmin, x); bxmax = fmaxf(bxmax, x);
      bymin = fminf(bymin, y); bymax = fmaxf(bymax, y);
      bzmin = fminf(bzmin, z); bzmax = fmaxf(bzmax, z);
      if ((pk >> 16) == 0u) *s_first = make_float4(x, y, z, 0.f);
    }
  }
  const bool anyv = p0 < M;
  float chunkmax = anyv ? 1e10f : -1e30f;   // first step always updates valid chunks
  u32 khi = 0u, klo = ~0xFFFFu;             // pad key; real chunks overwrite at k=1
  float bx = 0.f, by = 0.f, bz = 0.f;

  __syncthreads();   // s_ps reads done (s_k overlays it); s_first visible
  float4 f0 = *s_first;
  float lastx = f0.x, lasty = f0.y, lastz = f0.z;
  if (tid == 0) s_k[0] = f0;

  int bufc = 0;
  for (int k = 1; k < K; ++k) {
    float dxl = fmaxf(fmaxf(bxmin - lastx, lastx - bxmax), 0.0f);
    float dyl = fmaxf(fmaxf(bymin - lasty, lasty - bymax), 0.0f);
    float dzl = fmaxf(fmaxf(bzmin - lastz, lastz - bzmax), 0.0f);
    float lb2 = dxl * dxl; lb2 += dyl * dyl; lb2 += dzl * dzl;
    if (lb2 * 0.9999f < chunkmax) {
      float nmax = -1e30f; u32 nc = 0xFFFFu;
      float nx = 0.f, ny = 0.f, nz = 0.f;
#pragma unroll
      for (int j = 0; j < NL; ++j) {
        float dx = lx[j] - lastx;
        float dy = ly[j] - lasty;
        float dz = lz[j] - lastz;
        float d = dx * dx; d += dy * dy; d += dz * dz;   // exact reference sequence
        float nd = fminf(ld[j], d);
        ld[j] = nd;
        bool g = (nd > nmax) || ((nd == nmax) && ((u32)lc[j] < nc));
        nmax = g ? nd : nmax;
        nc = g ? (u32)lc[j] : nc;
        nx = g ? lx[j] : nx;
        ny = g ? ly[j] : ny;
        nz = g ? lz[j] : nz;
      }
      chunkmax = nmax;
      khi = __float_as_uint(nmax);   // nmax >= 0 always -> bit order == value order
      klo = ~nc;
      bx = nx; by = ny; bz = nz;
    }
    // wave u64-key max via DPP (VALU only), broadcast from lane 63
    u32 rlo = klo, rhi = khi;
    DPP_MAXK(rlo, rhi, 0x111);  // row_shr:1
    DPP_MAXK(rlo, rhi, 0x112);  // row_shr:2
    DPP_MAXK(rlo, rhi, 0x114);  // row_shr:4
    DPP_MAXK(rlo, rhi, 0x118);  // row_shr:8
    DPP_MAXK(rlo, rhi, 0x142);  // row_bcast:15
    DPP_MAXK(rlo, rhi, 0x143);  // row_bcast:31
    u32 wlo = (u32)__builtin_amdgcn_readlane((int)rlo, 63);
    u32 whi = (u32)__builtin_amdgcn_readlane((int)rhi, 63);
    if (klo == wlo && khi == whi) {   // unique winner (c unique); all-pad waves write same value
      s_key[bufc][wv] = ((u64)whi << 32) | (u64)wlo;
      s_cxyz[bufc][wv] = make_float4(bx, by, bz, 0.f);
    }
    __syncthreads();
    u64 best = s_key[bufc][0];
    int cw = 0;
#pragma unroll
    for (int w = 1; w < NW; ++w) {
      u64 cc = s_key[bufc][w];
      if (cc > best) { best = cc; cw = w; }
    }
    float4 kk = s_cxyz[bufc][cw];
    lastx = kk.x; lasty = kk.y; lastz = kk.z;
    if (tid == 0) s_k[k] = kk;
    bufc ^= 1;
  }
}

// ---------------------------------------------------------------- FPS: 6 blocks = (batch, band)
__launch_bounds__(1024)
__global__ void k_fps(const float* __restrict__ pts, const float* __restrict__ rngv,
                      float* __restrict__ out2) {
#pragma clang fp contract(off)
  const int blk = blockIdx.x;
  const int band = blk % 3, batch = blk / 3;
  const int K = (band == 0) ? 1024 : 512;
  const int off = (band == 0) ? 0 : (band == 1 ? 1024 : 1536);
  const int base = batch * NPTS_;

  __shared__ __align__(16) u32 s_ps[NPTS_];   // 64KB: (c<<16)|orig per sorted slot
  __shared__ int s_cnt[256];                  // cell hist -> exclusive offsets -> cursors
  __shared__ int s_wsum[16];
  __shared__ u64 s_key[2][16];
  __shared__ float4 s_cxyz[2][16];
  __shared__ float4 s_first;

  float4* s_k = reinterpret_cast<float4*>(s_ps);   // 16KB overlay; s_ps dead after slot load

  const int tid = threadIdx.x, lane = tid & 63, wv = tid >> 6;

  // ---- mask own contiguous 16-point chunk (order-preserving compaction index c)
  unsigned int vm = 0u;
  for (int j = 0; j < 16; ++j) {
    float r = rngv[base + tid * 16 + j];
    bool sm = (r > 0.0f) && (r < 25.0f);
    bool lm = (r > 45.0f);
    bool v = (band == 0) ? sm : (band == 2 ? lm : (!lm && !sm));
    vm |= (v ? 1u : 0u) << j;
  }
  int cnt = __popc(vm);
  int inc = cnt;
  for (int d = 1; d < 64; d <<= 1) {
    int o = __shfl_up(inc, d);
    if (lane >= d) inc += o;
  }
  if (lane == 63) s_wsum[wv] = inc;
  if (tid < 256) s_cnt[tid] = 0;
  __syncthreads();
  int woff = 0, M = 0;
  for (int w = 0; w < 16; ++w) {
    if (w < wv) woff += s_wsum[w];
    M += s_wsum[w];
  }
  const int myoff0 = woff + inc - cnt;

  // ---- cell histogram
  unsigned int t = vm;
  while (t) {
    int b = __builtin_ctz(t); t &= t - 1;
    int gi = (base + tid * 16 + b) * 5;
    float x = pts[gi + 1], y = pts[gi + 2];
    atomicAdd(&s_cnt[cellof(band, x, y)], 1);
  }
  __syncthreads();
  // ---- exclusive prefix over 256 cells (wave 0, shfl scan)
  if (tid < 64) {
    int c0 = s_cnt[tid * 4 + 0], c1 = s_cnt[tid * 4 + 1];
    int c2 = s_cnt[tid * 4 + 2], c3 = s_cnt[tid * 4 + 3];
    int s = c0 + c1 + c2 + c3;
    for (int d = 1; d < 64; d <<= 1) {
      int o = __shfl_up(s, d);
      if (lane >= d) s += o;
    }
    int b0 = s - (c0 + c1 + c2 + c3);
    s_cnt[tid * 4 + 0] = b0;
    s_cnt[tid * 4 + 1] = b0 + c0;
    s_cnt[tid * 4 + 2] = b0 + c0 + c1;
    s_cnt[tid * 4 + 3] = b0 + c0 + c1 + c2;
  }
  __syncthreads();
  // ---- scatter into cell order (within-cell order arbitrary; results point-associated)
  t = vm;
  int c = myoff0;
  while (t) {
    int b = __builtin_ctz(t); t &= t - 1;
    int orig = tid * 16 + b;
    int gi = (base + orig) * 5;
    float x = pts[gi + 1], y = pts[gi + 2];
    int s = atomicAdd(&s_cnt[cellof(band, x, y)], 1);
    s_ps[s] = (u32)orig | ((u32)c << 16);
    ++c;
  }
  __syncthreads();

  // ---- band/M-dependent wave count + slot count
  int sel;  // 0:(4,12) 1:(4,16) 2:(8,16) 3:(16,16)
  if (band == 0) {
    if (M <= 3072) sel = 0;
    else if (M <= 4096) sel = 1;
    else if (M <= 8192) sel = 2;
    else sel = 3;
  } else {
    sel = (M <= 8192) ? 2 : 3;
  }
  const int nw = (sel <= 1) ? 4 : (sel == 2 ? 8 : 16);
  if (tid >= nw * 64) return;   // whole surplus waves exit; barriers track live waves

  if (sel == 0)      fps_core<4, 12>(tid, wv, M, K, base, pts, s_ps, s_k, s_key, s_cxyz, &s_first);
  else if (sel == 1) fps_core<4, 16>(tid, wv, M, K, base, pts, s_ps, s_k, s_key, s_cxyz, &s_first);
  else if (sel == 2) fps_core<8, 16>(tid, wv, M, K, base, pts, s_ps, s_k, s_key, s_cxyz, &s_first);
  else               fps_core<16, 16>(tid, wv, M, K, base, pts, s_ps, s_k, s_key, s_cxyz, &s_first);

  // ---- epilogue: stream keypoints to out2
  __syncthreads();
  const float batf = (float)batch;
  for (int i = tid; i < K; i += nw * 64) {
    int g = (batch * KTOT_ + off + i) * 4;
    float4 kk = s_k[i];
    out2[g + 0] = batf;
    out2[g + 1] = kk.x;
    out2[g + 2] = kk.y;
    out2[g + 3] = kk.z;
  }
}

// ---------------------------------------------------------------- bilinear BEV gather, native [B,C,H,W]
__launch_bounds__(256)
__global__ void k_bev(const float* __restrict__ sf, const float* __restrict__ out2,
                      float* __restrict__ out1) {
#pragma clang fp contract(off)
  int tid = threadIdx.x, lane = tid & 63, wv = tid >> 6;
  int g = blockIdx.x * 4 + wv;
  if (g >= ROWS_) return;
  int b = g >> 11;
  float xx = out2[g * 4 + 1], yy = out2[g * 4 + 2];
  float x = (xx - 0.0f) / 0.05f / 8.0f;
  float y = (yy - (-40.0f)) / 0.05f / 8.0f;
  int x0 = (int)floorf(x), y0 = (int)floorf(y);
  int x1 = x0 + 1, y1 = y0 + 1;
  x0 = min(max(x0, 0), IMW - 1); x1 = min(max(x1, 0), IMW - 1);
  y0 = min(max(y0, 0), IMH - 1); y1 = min(max(y1, 0), IMH - 1);
  float x0f = (float)x0, x1f = (float)x1, y0f = (float)y0, y1f = (float)y1;
  float wa = (x1f - x) * (y1f - y);
  float wb = (x1f - x) * (y - y0f);
  float wc = (x - x0f) * (y1f - y);
  float wd = (x - x0f) * (y - y0f);
  int oa = y0 * IMW + x0;
  int ob = y1 * IMW + x0;
  int oc = y0 * IMW + x1;
  int od = y1 * IMW + x1;
  const float* pb = sf + (size_t)b * IMC * IMH * IMW;
  for (int j = 0; j < 4; ++j) {
    int c = lane * 4 + j;
    const float* pc = pb + (size_t)c * (IMH * IMW);
    float o = pc[oa] * wa;
    o += pc[ob] * wb;
    o += pc[oc] * wc;
    o += pc[od] * wd;
    out1[(size_t)g * CIN_ + c] = o;
  }
}

// ---------------------------------------------------------------- SA: ball query + MLP + maxpool (wave per kp)
__launch_bounds__(256)
__global__ void k_sa(const float* __restrict__ pts, const float* __restrict__ out2,
                     const float* __restrict__ w0, const float* __restrict__ bn0,
                     const float* __restrict__ w1, const float* __restrict__ bn1,
                     float* __restrict__ out1) {
#pragma clang fp contract(off)
  __shared__ float s_w0[128];   // [2][4][16]
  __shared__ float s_w1[512];   // [2][16][16]
  __shared__ float s_s0[32], s_m0[32], s_b0[32];  // [2][16]
  __shared__ float s_s1[32], s_m1[32], s_b1[32];
  int tid = threadIdx.x;
  for (int i = tid; i < 128; i += 256) s_w0[i] = w0[i];
  for (int i = tid; i < 512; i += 256) s_w1[i] = w1[i];
  if (tid < 32) {
    int rad = tid >> 4, c = tid & 15;
    int bb = rad * 64;
    {
      float gg = bn0[bb + c], bbt = bn0[bb + 16 + c];
      float mm = bn0[bb + 32 + c], vv = bn0[bb + 48 + c];
      s_s0[tid] = gg / sqrtf(vv + 1e-5f); s_m0[tid] = mm; s_b0[tid] = bbt;
    }
    {
      float gg = bn1[bb + c], bbt = bn1[bb + 16 + c];
      float mm = bn1[bb + 32 + c], vv = bn1[bb + 48 + c];
      s_s1[tid] = gg / sqrtf(vv + 1e-5f); s_m1[tid] = mm; s_b1[tid] = bbt;
    }
  }
  __syncthreads();

  int lane = tid & 63, wv = tid >> 6;
  int g = blockIdx.x * 4 + wv;
  if (g >= ROWS_) return;
  int batch = g >> 11;
  int base = batch * NPTS_;
  float kx = out2[g * 4 + 1];
  float ky = out2[g * 4 + 2];
  float kz = out2[g * 4 + 3];

  int myrad = (lane >> 4) & 1, myslot = lane & 15;
  int c1 = 0, c2 = 0, first1 = -1, first2 = -1, myidx = -1;
  for (int r = 0; r < NPTS_ / 64; ++r) {
    int gi = (base + r * 64 + lane) * 5;
    float dx = kx - pts[gi + 1];
    float dy = ky - pts[gi + 2];
    float dz = kz - pts[gi + 3];
    float d = dx * dx;
    d += dy * dy;
    d += dz * dz;
    unsigned long long m1 = __ballot(d < 1.0f);
    unsigned long long m2 = __ballot(d < 4.0f);
    while (m1 && c1 < 16) {
      int bpos = __builtin_ctzll(m1); m1 &= m1 - 1;
      int pi = r * 64 + bpos;
      if (c1 == 0) first1 = pi;
      if (lane < 32 && myrad == 0 && c1 == myslot) myidx = pi;
      ++c1;
    }
    while (m2 && c2 < 16) {
      int bpos = __builtin_ctzll(m2); m2 &= m2 - 1;
      int pi = r * 64 + bpos;
      if (c2 == 0) first2 = pi;
      if (lane < 32 && myrad == 1 && c2 == myslot) myidx = pi;
      ++c2;
    }
    if (c1 >= 16 && c2 >= 16) break;
  }
  int fi = (myrad == 0) ? first1 : first2;
  bool use = (lane < 32) && (fi >= 0);
  if (myidx < 0) myidx = (fi >= 0) ? fi : 0;
  float gx = 0.f, gy = 0.f, gz = 0.f, gf = 0.f;
  if (use) {
    int gi = (base + myidx) * 5;
    gx = pts[gi + 1] - kx;
    gy = pts[gi + 2] - ky;
    gz = pts[gi + 3] - kz;
    gf = pts[gi + 4];
  }
  const float* W0 = s_w0 + myrad * 64;    // [4][16]
  const float* W1 = s_w1 + myrad * 256;   // [16][16]
  int bc = myrad * 16;
  float h1[16];
  for (int c = 0; c < 16; ++c) {
    float a = gx * W0[c];
    a += gy * W0[16 + c];
    a += gz * W0[32 + c];
    a += gf * W0[48 + c];
    h1[c] = fmaxf((a - s_m0[bc + c]) * s_s0[bc + c] + s_b0[bc + c], 0.f);
  }
  for (int c = 0; c < 16; ++c) {
    float a = 0.f;
    for (int k = 0; k < 16; ++k) a += h1[k] * W1[k * 16 + c];
    float h2 = fmaxf((a - s_m1[bc + c]) * s_s1[bc + c] + s_b1[bc + c], 0.f);
    h2 = fmaxf(h2, __shfl_xor(h2, 1));
    h2 = fmaxf(h2, __shfl_xor(h2, 2));
    h2 = fmaxf(h2, __shfl_xor(h2, 4));
    h2 = fmaxf(h2, __shfl_xor(h2, 8));
    if (lane < 32 && myslot == 0) {
      int col = 256 + myrad * 16 + c;
      out1[(size_t)g * CIN_ + col] = h2;
    }
  }
}

// ---------------------------------------------------------------- fusion: [4096,288]@[288,128] + BN + ReLU
__launch_bounds__(128)
__global__ void k_fuse(const float* __restrict__ out1, const float* __restrict__ fw,
                       const float* __restrict__ fbn, float* __restrict__ out0) {
  int r = blockIdx.x, c = threadIdx.x;
  __shared__ float sA[CIN_];
  for (int i = c; i < CIN_; i += 128) sA[i] = out1[(size_t)r * CIN_ + i];
  __syncthreads();
  float acc = 0.f;
  for (int k = 0; k < CIN_; ++k) acc += sA[k] * fw[k * COUT_ + c];
  float gg = fbn[c], bb = fbn[COUT_ + c];
  float mm = fbn[2 * COUT_ + c], vv = fbn[3 * COUT_ + c];
  float sc = gg / sqrtf(vv + 1e-5f);
  float o = fmaxf((acc - mm) * sc + bb, 0.f);
  out0[(size_t)r * COUT_ + c] = o;
}

// ---------------------------------------------------------------- launch (ZERO d_ws usage)
extern "C" void kernel_launch(void* const* d_in, const int* in_sizes, int n_in,
                              void* d_out, int out_size, void* d_ws, size_t ws_size,
                              hipStream_t stream) {
  const float* points = (const float*)d_in[0];
  const float* rng    = (const float*)d_in[1];
  const float* sf     = (const float*)d_in[2];
  const float* w0     = (const float*)d_in[3];
  const float* bn0    = (const float*)d_in[4];
  const float* w1     = (const float*)d_in[5];
  const float* bn1    = (const float*)d_in[6];
  const float* fw     = (const float*)d_in[7];
  const float* fbn    = (const float*)d_in[8];

  float* out0 = (float*)d_out;                         // fused [4096,128]
  float* out1 = out0 + (size_t)ROWS_ * COUT_;          // feats [4096,288]
  float* out2 = out1 + (size_t)ROWS_ * CIN_;           // point_coords [4096,4]

  k_fps<<<6, 1024, 0, stream>>>(points, rng, out2);
  k_bev<<<ROWS_ / 4, 256, 0, stream>>>(sf, out2, out1);
  k_sa<<<ROWS_ / 4, 256, 0, stream>>>(points, out2, w0, bn0, w1, bn1, out1);
  k_fuse<<<ROWS_, 128, 0, stream>>>(out1, fw, fbn, out0);
}

// Round 2
// 1157.134 us; speedup vs baseline: 1.4358x; 1.4358x over previous
//
#include <hip/hip_runtime.h>
#include <hip/hip_bf16.h>
#include <climits>

#define NB 2
#define NPTS_ 16384
#define IMH 200
#define IMW 176
#define IMC 256
#define KTOT_ 2048
#define ROWS_ 4096
#define CIN_ 288
#define COUT_ 128

typedef unsigned long long u64;
typedef unsigned int u32;

// DPP wave64 reduction stages (VALU-only; result lands in lane 63).
#define DPP_MAXF(v, ctrl)                                                              \
  do {                                                                                 \
    int _s = __builtin_amdgcn_update_dpp(__float_as_int(v), __float_as_int(v), (ctrl), \
                                         0xF, 0xF, false);                             \
    (v) = fmaxf((v), __int_as_float(_s));                                              \
  } while (0)
#define DPP_MINU(v, ctrl)                                                              \
  do {                                                                                 \
    int _s = __builtin_amdgcn_update_dpp((int)(v), (int)(v), (ctrl), 0xF, 0xF, false); \
    (v) = ((u32)_s < (v)) ? (u32)_s : (v);                                             \
  } while (0)

// ---------------------------------------------------------------- FPS core (round-0 structure + lazy top-2 batching)
// NW waves, slot p = tid + j*NW*64. Per ROUND: one scan + one reduction yields the
// exact global top-1 (w) AND top-2 (r) under key order (dist, ~slot)  (slot order ==
// original order: compaction is order-preserving). Commit w; additionally commit r
// in the SAME round iff d2(r,w) >= dist_r (then min(dist_r, d2(r,w)) == dist_r exactly,
// so r is still the argmax after w's update: for i<r dist_i < dist_r strictly held
// before, and dists only decrease -> first-index argmax is r. Bit-exact vs reference).
// Next round's scan mins against both pending points in reference order.
template <int NW, int NL>
__device__ __forceinline__ void fps_core(
    int tid, int lane, int wv, int M, int K, int base,
    const float* __restrict__ pts,
    const unsigned short* __restrict__ s_idx,
    float4* __restrict__ s_k,
    u64 (* __restrict__ s_key)[16],
    float4 (* __restrict__ s_cxyz)[16],
    u64 (* __restrict__ s_key2)[16],
    float4 (* __restrict__ s_cxyz2)[16]) {
#pragma clang fp contract(off)
  constexpr int STRIDE = NW * 64;
  float lx[NL], ly[NL], lz[NL], ld[NL];
#pragma unroll
  for (int j = 0; j < NL; ++j) {
    int p = tid + j * STRIDE;
    bool v = p < M;
    int oi = v ? (int)s_idx[p] : 0;
    int gi = (base + oi) * 5;
    lx[j] = pts[gi + 1];
    ly[j] = pts[gi + 2];
    lz[j] = pts[gi + 3];
    ld[j] = v ? 1e10f : -1.0f;   // invalid slots pinned at -1: never selected
  }
  int gi0 = (base + (int)s_idx[0]) * 5;
  float ax = pts[gi0 + 1], ay = pts[gi0 + 2], az = pts[gi0 + 3];   // pending A (always)
  float bx2 = 0.f, by2 = 0.f, bz2 = 0.f;                           // pending B (if two)
  bool two = false;
  if (tid == 0) s_k[0] = make_float4(ax, ay, az, 0.f);

  int bufc = 0;
  int k = 1;
  while (k < K) {
    // ---- scan: min vs pending A, then (if dual) pending B — reference order
#pragma unroll
    for (int j = 0; j < NL; ++j) {
      float dx = lx[j] - ax;
      float dy = ly[j] - ay;
      float dz = lz[j] - az;
      float d = dx * dx;
      d += dy * dy;
      d += dz * dz;
      ld[j] = fminf(ld[j], d);
    }
    if (two) {   // block-uniform branch
#pragma unroll
      for (int j = 0; j < NL; ++j) {
        float dx = lx[j] - bx2;
        float dy = ly[j] - by2;
        float dz = lz[j] - bz2;
        float d = dx * dx;
        d += dy * dy;
        d += dz * dz;
        ld[j] = fminf(ld[j], d);
      }
    }
    float bd = -1.0f;
#pragma unroll
    for (int j = 0; j < NL; ++j) bd = fmaxf(bd, ld[j]);

    // ---- extraction 1: smallest slot achieving bd (descending -> first index)
    int bj = 0;
    float bx = lx[0], by = ly[0], bz = lz[0];
#pragma unroll
    for (int j = NL - 1; j >= 0; --j) {
      if (ld[j] == bd) { bj = j; bx = lx[j]; by = ly[j]; bz = lz[j]; }
    }
    int bp = tid + bj * STRIDE;

    // ---- wave reduce 1: max-d via DPP, then min-p among ties
    float rd = bd;
    DPP_MAXF(rd, 0x111);
    DPP_MAXF(rd, 0x112);
    DPP_MAXF(rd, 0x114);
    DPP_MAXF(rd, 0x118);
    DPP_MAXF(rd, 0x142);
    DPP_MAXF(rd, 0x143);
    float maxd = __int_as_float(__builtin_amdgcn_readlane(__float_as_int(rd), 63));
    u32 pc = (bd == maxd) ? (u32)bp : 0xFFFFFFFFu;
    u32 rp = pc;
    DPP_MINU(rp, 0x111);
    DPP_MINU(rp, 0x112);
    DPP_MINU(rp, 0x114);
    DPP_MINU(rp, 0x118);
    DPP_MINU(rp, 0x142);
    DPP_MINU(rp, 0x143);
    u32 wp = (u32)__builtin_amdgcn_readlane((int)rp, 63);
    bool iwin = (pc == wp);
    if (iwin) {
      s_key[bufc][wv] = ((u64)__float_as_uint(maxd) << 32) | (u32)(~wp);
      s_cxyz[bufc][wv] = make_float4(bx, by, bz, 0.f);
    }

    // ---- per-lane candidate for global 2nd:
    //      winner lane offers its local 2nd (excluding bj); others their local 1st
    float bd2 = -1.0f;
#pragma unroll
    for (int j = 0; j < NL; ++j) bd2 = fmaxf(bd2, (j == bj) ? -1.0f : ld[j]);
    int bj2 = 0;
    float cx2 = lx[0], cy2 = ly[0], cz2 = lz[0];
#pragma unroll
    for (int j = NL - 1; j >= 0; --j) {
      if (ld[j] == bd2 && j != bj) { bj2 = j; cx2 = lx[j]; cy2 = ly[j]; cz2 = lz[j]; }
    }
    float c2 = iwin ? bd2 : bd;
    u32 cp  = iwin ? (u32)(tid + bj2 * STRIDE) : (u32)bp;
    float wx = iwin ? cx2 : bx;
    float wy = iwin ? cy2 : by;
    float wz = iwin ? cz2 : bz;

    // ---- wave reduce 2 (same pattern)
    float rd2 = c2;
    DPP_MAXF(rd2, 0x111);
    DPP_MAXF(rd2, 0x112);
    DPP_MAXF(rd2, 0x114);
    DPP_MAXF(rd2, 0x118);
    DPP_MAXF(rd2, 0x142);
    DPP_MAXF(rd2, 0x143);
    float maxd2 = __int_as_float(__builtin_amdgcn_readlane(__float_as_int(rd2), 63));
    u32 pc2 = (c2 == maxd2) ? cp : 0xFFFFFFFFu;
    u32 rp2 = pc2;
    DPP_MINU(rp2, 0x111);
    DPP_MINU(rp2, 0x112);
    DPP_MINU(rp2, 0x114);
    DPP_MINU(rp2, 0x118);
    DPP_MINU(rp2, 0x142);
    DPP_MINU(rp2, 0x143);
    u32 wp2 = (u32)__builtin_amdgcn_readlane((int)rp2, 63);
    if (pc2 == wp2) {
      // clamp: negative (pad) candidates write a null key (loses to any real key)
      s_key2[bufc][wv] = (maxd2 > 0.0f)
          ? (((u64)__float_as_uint(maxd2) << 32) | (u64)(u32)(~wp2))
          : 0ull;
      s_cxyz2[bufc][wv] = make_float4(wx, wy, wz, 0.f);
    }
    __syncthreads();

    // ---- cross-wave: top1 over wave keys; top2 over (others' top1) U (winner wave's top2)
    u64 b1 = s_key[bufc][0];
    int cw1 = 0;
#pragma unroll
    for (int w = 1; w < NW; ++w) {
      u64 cc = s_key[bufc][w];
      if (cc > b1) { b1 = cc; cw1 = w; }
    }
    u64 b2k = 0;
    int cw2 = 0;
#pragma unroll
    for (int w = 0; w < NW; ++w) {
      u64 cc = (w == cw1) ? 0ull : s_key[bufc][w];
      if (cc > b2k) { b2k = cc; cw2 = w; }
    }
    u64 c2k = s_key2[bufc][cw1];
    bool from2 = (c2k > b2k);
    if (from2) b2k = c2k;
    float4 k1 = s_cxyz[bufc][cw1];
    float4 kc2 = from2 ? s_cxyz2[bufc][cw1] : s_cxyz[bufc][cw2];

    // ---- validity of lazy second commit (exact: same fp32 sequence as next scan)
    float distr = __uint_as_float((u32)(b2k >> 32));
    float ddx = kc2.x - k1.x;
    float ddy = kc2.y - k1.y;
    float ddz = kc2.z - k1.z;
    float d2rw = ddx * ddx;
    d2rw += ddy * ddy;
    d2rw += ddz * ddz;
    bool valid = (d2rw >= distr) && (distr > 0.0f) && (k + 1 < K);

    if (tid == 0) {
      s_k[k] = k1;
      if (valid) s_k[k + 1] = kc2;
    }
    ax = k1.x; ay = k1.y; az = k1.z;
    bx2 = kc2.x; by2 = kc2.y; bz2 = kc2.z;
    two = valid;
    k += valid ? 2 : 1;
    bufc ^= 1;
  }
}

// ---------------------------------------------------------------- FPS: 6 blocks = (batch, band), 1024 threads
__launch_bounds__(1024)
__global__ void k_fps(const float* __restrict__ pts, const float* __restrict__ rngv,
                      float* __restrict__ out2) {
#pragma clang fp contract(off)
  const int blk = blockIdx.x;
  const int band = blk % 3, batch = blk / 3;
  const int K = (band == 0) ? 1024 : 512;
  const int off = (band == 0) ? 0 : (band == 1 ? 1024 : 1536);
  const int base = batch * NPTS_;

  __shared__ unsigned short s_idx[NPTS_];   // 32 KB compacted -> original idx
  __shared__ float4 s_k[1024];              // 16 KB selected keypoints
  __shared__ u64 s_key[2][16];
  __shared__ float4 s_cxyz[2][16];
  __shared__ u64 s_key2[2][16];
  __shared__ float4 s_cxyz2[2][16];
  __shared__ int s_wsum[16];

  const int tid = threadIdx.x, lane = tid & 63, wv = tid >> 6;

  // ---- mask own contiguous 16-point chunk (order-preserving compaction)
  unsigned int vm = 0u;
  for (int j = 0; j < 16; ++j) {
    float r = rngv[base + tid * 16 + j];
    bool sm = (r > 0.0f) && (r < 25.0f);
    bool lm = (r > 45.0f);
    bool v = (band == 0) ? sm : (band == 2 ? lm : (!lm && !sm));
    vm |= (v ? 1u : 0u) << j;
  }
  int cnt = __popc(vm);
  int inc = cnt;
  for (int d = 1; d < 64; d <<= 1) {
    int o = __shfl_up(inc, d);
    if (lane >= d) inc += o;
  }
  if (lane == 63) s_wsum[wv] = inc;
  __syncthreads();
  int woff = 0, M = 0;
  for (int w = 0; w < 16; ++w) {
    if (w < wv) woff += s_wsum[w];
    M += s_wsum[w];
  }
  int myoff = woff + inc - cnt;
  unsigned int t = vm;
  while (t) {
    int b = __builtin_ctz(t);
    t &= t - 1;
    s_idx[myoff++] = (unsigned short)(tid * 16 + b);
  }
  __syncthreads();

  // ---- band/M-dependent wave count + slot count (all register-resident)
  int sel;  // 0:(4,12) 1:(4,16) 2:(8,16) 3:(16,16)
  if (band == 0) {
    if (M <= 3072) sel = 0;
    else if (M <= 4096) sel = 1;
    else if (M <= 8192) sel = 2;
    else sel = 3;
  } else {
    sel = (M <= 8192) ? 2 : 3;
  }
  const int nw = (sel <= 1) ? 4 : (sel == 2 ? 8 : 16);
  if (tid >= nw * 64) return;   // surplus waves exit; barriers track live waves

  if (sel == 0)      fps_core<4, 12>(tid, lane, wv, M, K, base, pts, s_idx, s_k, s_key, s_cxyz, s_key2, s_cxyz2);
  else if (sel == 1) fps_core<4, 16>(tid, lane, wv, M, K, base, pts, s_idx, s_k, s_key, s_cxyz, s_key2, s_cxyz2);
  else if (sel == 2) fps_core<8, 16>(tid, lane, wv, M, K, base, pts, s_idx, s_k, s_key, s_cxyz, s_key2, s_cxyz2);
  else               fps_core<16, 16>(tid, lane, wv, M, K, base, pts, s_idx, s_k, s_key, s_cxyz, s_key2, s_cxyz2);

  // ---- epilogue: stream keypoints to out2
  __syncthreads();
  const float batf = (float)batch;
  for (int i = tid; i < K; i += nw * 64) {
    int g = (batch * KTOT_ + off + i) * 4;
    float4 kk = s_k[i];
    out2[g + 0] = batf;
    out2[g + 1] = kk.x;
    out2[g + 2] = kk.y;
    out2[g + 3] = kk.z;
  }
}

// ---------------------------------------------------------------- bilinear BEV gather, native [B,C,H,W]
__launch_bounds__(256)
__global__ void k_bev(const float* __restrict__ sf, const float* __restrict__ out2,
                      float* __restrict__ out1) {
#pragma clang fp contract(off)
  int tid = threadIdx.x, lane = tid & 63, wv = tid >> 6;
  int g = blockIdx.x * 4 + wv;
  if (g >= ROWS_) return;
  int b = g >> 11;
  float xx = out2[g * 4 + 1], yy = out2[g * 4 + 2];
  float x = (xx - 0.0f) / 0.05f / 8.0f;
  float y = (yy - (-40.0f)) / 0.05f / 8.0f;
  int x0 = (int)floorf(x), y0 = (int)floorf(y);
  int x1 = x0 + 1, y1 = y0 + 1;
  x0 = min(max(x0, 0), IMW - 1); x1 = min(max(x1, 0), IMW - 1);
  y0 = min(max(y0, 0), IMH - 1); y1 = min(max(y1, 0), IMH - 1);
  float x0f = (float)x0, x1f = (float)x1, y0f = (float)y0, y1f = (float)y1;
  float wa = (x1f - x) * (y1f - y);
  float wb = (x1f - x) * (y - y0f);
  float wc = (x - x0f) * (y1f - y);
  float wd = (x - x0f) * (y - y0f);
  int oa = y0 * IMW + x0;
  int ob = y1 * IMW + x0;
  int oc = y0 * IMW + x1;
  int od = y1 * IMW + x1;
  const float* pb = sf + (size_t)b * IMC * IMH * IMW;
  for (int j = 0; j < 4; ++j) {
    int c = lane * 4 + j;
    const float* pc = pb + (size_t)c * (IMH * IMW);
    float o = pc[oa] * wa;
    o += pc[ob] * wb;
    o += pc[oc] * wc;
    o += pc[od] * wd;
    out1[(size_t)g * CIN_ + c] = o;
  }
}

// ---------------------------------------------------------------- SA: ball query + MLP + maxpool (wave per kp)
__launch_bounds__(256)
__global__ void k_sa(const float* __restrict__ pts, const float* __restrict__ out2,
                     const float* __restrict__ w0, const float* __restrict__ bn0,
                     const float* __restrict__ w1, const float* __restrict__ bn1,
                     float* __restrict__ out1) {
#pragma clang fp contract(off)
  __shared__ float s_w0[128];   // [2][4][16]
  __shared__ float s_w1[512];   // [2][16][16]
  __shared__ float s_s0[32], s_m0[32], s_b0[32];  // [2][16]
  __shared__ float s_s1[32], s_m1[32], s_b1[32];
  int tid = threadIdx.x;
  for (int i = tid; i < 128; i += 256) s_w0[i] = w0[i];
  for (int i = tid; i < 512; i += 256) s_w1[i] = w1[i];
  if (tid < 32) {
    int rad = tid >> 4, c = tid & 15;
    int bb = rad * 64;
    {
      float gg = bn0[bb + c], bbt = bn0[bb + 16 + c];
      float mm = bn0[bb + 32 + c], vv = bn0[bb + 48 + c];
      s_s0[tid] = gg / sqrtf(vv + 1e-5f); s_m0[tid] = mm; s_b0[tid] = bbt;
    }
    {
      float gg = bn1[bb + c], bbt = bn1[bb + 16 + c];
      float mm = bn1[bb + 32 + c], vv = bn1[bb + 48 + c];
      s_s1[tid] = gg / sqrtf(vv + 1e-5f); s_m1[tid] = mm; s_b1[tid] = bbt;
    }
  }
  __syncthreads();

  int lane = tid & 63, wv = tid >> 6;
  int g = blockIdx.x * 4 + wv;
  if (g >= ROWS_) return;
  int batch = g >> 11;
  int base = batch * NPTS_;
  float kx = out2[g * 4 + 1];
  float ky = out2[g * 4 + 2];
  float kz = out2[g * 4 + 3];

  int myrad = (lane >> 4) & 1, myslot = lane & 15;
  int c1 = 0, c2 = 0, first1 = -1, first2 = -1, myidx = -1;
  for (int r = 0; r < NPTS_ / 64; ++r) {
    int gi = (base + r * 64 + lane) * 5;
    float dx = kx - pts[gi + 1];
    float dy = ky - pts[gi + 2];
    float dz = kz - pts[gi + 3];
    float d = dx * dx;
    d += dy * dy;
    d += dz * dz;
    unsigned long long m1 = __ballot(d < 1.0f);
    unsigned long long m2 = __ballot(d < 4.0f);
    while (m1 && c1 < 16) {
      int bpos = __builtin_ctzll(m1); m1 &= m1 - 1;
      int pi = r * 64 + bpos;
      if (c1 == 0) first1 = pi;
      if (lane < 32 && myrad == 0 && c1 == myslot) myidx = pi;
      ++c1;
    }
    while (m2 && c2 < 16) {
      int bpos = __builtin_ctzll(m2); m2 &= m2 - 1;
      int pi = r * 64 + bpos;
      if (c2 == 0) first2 = pi;
      if (lane < 32 && myrad == 1 && c2 == myslot) myidx = pi;
      ++c2;
    }
    if (c1 >= 16 && c2 >= 16) break;
  }
  int fi = (myrad == 0) ? first1 : first2;
  bool use = (lane < 32) && (fi >= 0);
  if (myidx < 0) myidx = (fi >= 0) ? fi : 0;
  float gx = 0.f, gy = 0.f, gz = 0.f, gf = 0.f;
  if (use) {
    int gi = (base + myidx) * 5;
    gx = pts[gi + 1] - kx;
    gy = pts[gi + 2] - ky;
    gz = pts[gi + 3] - kz;
    gf = pts[gi + 4];
  }
  const float* W0 = s_w0 + myrad * 64;    // [4][16]
  const float* W1 = s_w1 + myrad * 256;   // [16][16]
  int bc = myrad * 16;
  float h1[16];
  for (int c = 0; c < 16; ++c) {
    float a = gx * W0[c];
    a += gy * W0[16 + c];
    a += gz * W0[32 + c];
    a += gf * W0[48 + c];
    h1[c] = fmaxf((a - s_m0[bc + c]) * s_s0[bc + c] + s_b0[bc + c], 0.f);
  }
  for (int c = 0; c < 16; ++c) {
    float a = 0.f;
    for (int k = 0; k < 16; ++k) a += h1[k] * W1[k * 16 + c];
    float h2 = fmaxf((a - s_m1[bc + c]) * s_s1[bc + c] + s_b1[bc + c], 0.f);
    h2 = fmaxf(h2, __shfl_xor(h2, 1));
    h2 = fmaxf(h2, __shfl_xor(h2, 2));
    h2 = fmaxf(h2, __shfl_xor(h2, 4));
    h2 = fmaxf(h2, __shfl_xor(h2, 8));
    if (lane < 32 && myslot == 0) {
      int col = 256 + myrad * 16 + c;
      out1[(size_t)g * CIN_ + col] = h2;
    }
  }
}

// ---------------------------------------------------------------- fusion: [4096,288]@[288,128] + BN + ReLU
__launch_bounds__(128)
__global__ void k_fuse(const float* __restrict__ out1, const float* __restrict__ fw,
                       const float* __restrict__ fbn, float* __restrict__ out0) {
  int r = blockIdx.x, c = threadIdx.x;
  __shared__ float sA[CIN_];
  for (int i = c; i < CIN_; i += 128) sA[i] = out1[(size_t)r * CIN_ + i];
  __syncthreads();
  float acc = 0.f;
  for (int k = 0; k < CIN_; ++k) acc += sA[k] * fw[k * COUT_ + c];
  float gg = fbn[c], bb = fbn[COUT_ + c];
  float mm = fbn[2 * COUT_ + c], vv = fbn[3 * COUT_ + c];
  float sc = gg / sqrtf(vv + 1e-5f);
  float o = fmaxf((acc - mm) * sc + bb, 0.f);
  out0[(size_t)r * COUT_ + c] = o;
}

// ---------------------------------------------------------------- launch (ZERO d_ws usage)
extern "C" void kernel_launch(void* const* d_in, const int* in_sizes, int n_in,
                              void* d_out, int out_size, void* d_ws, size_t ws_size,
                              hipStream_t stream) {
  const float* points = (const float*)d_in[0];
  const float* rng    = (const float*)d_in[1];
  const float* sf     = (const float*)d_in[2];
  const float* w0     = (const float*)d_in[3];
  const float* bn0    = (const float*)d_in[4];
  const float* w1     = (const float*)d_in[5];
  const float* bn1    = (const float*)d_in[6];
  const float* fw     = (const float*)d_in[7];
  const float* fbn    = (const float*)d_in[8];

  float* out0 = (float*)d_out;                         // fused [4096,128]
  float* out1 = out0 + (size_t)ROWS_ * COUT_;          // feats [4096,288]
  float* out2 = out1 + (size_t)ROWS_ * CIN_;           // point_coords [4096,4]

  k_fps<<<6, 1024, 0, stream>>>(points, rng, out2);
  k_bev<<<ROWS_ / 4, 256, 0, stream>>>(sf, out2, out1);
  k_sa<<<ROWS_ / 4, 256, 0, stream>>>(points, out2, w0, bn0, w1, bn1, out1);
  k_fuse<<<ROWS_, 128, 0, stream>>>(out1, fw, fbn, out0);
}